// Round 3
// baseline (94.749 us; speedup 1.0000x reference)
//
#include <hip/hip_runtime.h>
#include <hip/hip_bf16.h>
#include <math.h>

// BlockSoftmaxLinearHybrid: B=2,H=16,L=4096,D=64,F=64,S=64
constexpr int Bc = 2, Hc = 16, Lc = 4096, Dc = 64, Fc = 64;
constexpr int Sc = 64;
constexpr int Nc = Lc / Sc;      // 64
constexpr int F2 = 2 * Fc;       // 128
constexpr int BH = Bc * Hc;      // 32
constexpr int NBLK = BH * Nc;    // 2048
constexpr float EPSf = 1e-6f;
constexpr float SCALE = 0.125f;  // D^-0.5

typedef short short8 __attribute__((ext_vector_type(8)));     // 8 bf16 MFMA A/B frag
typedef float f32x4 __attribute__((ext_vector_type(4)));      // MFMA C/D frag
typedef unsigned short ushort;
typedef ushort ushort4v __attribute__((ext_vector_type(4)));

__device__ inline ushort f2bf(float x) {            // fp32 -> bf16 RNE
    unsigned u = __builtin_bit_cast(unsigned, x);
    u = (u + 0x7fffu + ((u >> 16) & 1u)) >> 16;
    return (ushort)u;
}
__device__ inline float bf2f(ushort h) {
    return __builtin_bit_cast(float, ((unsigned)h) << 16);
}
__device__ inline f32x4 zero4() { f32x4 z = {0.f, 0.f, 0.f, 0.f}; return z; }

__device__ inline f32x4 mfma(short8 a, short8 b, f32x4 c) {
    return __builtin_amdgcn_mfma_f32_16x16x32_bf16(a, b, c, 0, 0, 0);
}

// LDS fragment read, XOR-swizzled 16B chunks (T2)
__device__ inline short8 ldfrag(const char* L, int row, int chunk, int rowbytes, int mask) {
    return *(const short8*)(L + row * rowbytes + ((chunk * 16) ^ ((row & mask) << 4)));
}

// Direct global fragment: 8 consecutive fp32 at [row][chunk*8] of row-major [.][64] -> bf16
__device__ inline short8 gfrag_f32(const float* __restrict__ base, int row, int chunk) {
    const float4* p = (const float4*)(base + row * 64 + chunk * 8);
    float4 a = p[0], b = p[1];
    short8 r;
    r[0] = (short)f2bf(a.x); r[1] = (short)f2bf(a.y); r[2] = (short)f2bf(a.z); r[3] = (short)f2bf(a.w);
    r[4] = (short)f2bf(b.x); r[5] = (short)f2bf(b.y); r[6] = (short)f2bf(b.z); r[7] = (short)f2bf(b.w);
    return r;
}
// Direct global fragment from bf16 row-major [.][rowlen]
__device__ inline short8 gfrag_bf16(const ushort* __restrict__ base, int row, int chunk, int rowlen) {
    return *(const short8*)(base + row * rowlen + chunk * 8);
}

// cooperative transpose stage: src [64][64] fp32 row-major -> dst[j][i] bf16 swz (mask 7)
__device__ inline void stage_tr(const float* __restrict__ src, char* dst, int t) {
    int j = t & 63, g = t >> 6;
    #pragma unroll
    for (int i = 0; i < 4; ++i) {
        int i0 = g * 4 + i * 16;
        ushort4v hv;
        #pragma unroll
        for (int jj = 0; jj < 4; ++jj) hv[jj] = f2bf(src[(i0 + jj) * 64 + j]);
        *(ushort4v*)(dst + j * 128 + ((2 * i0) ^ ((j & 7) << 4))) = hv;
    }
}

// ---------------------------------------------------------------------------
// passW: Wt[h][f][d] = bf16(W[h][d][f])  (one-time, 16 blocks)
// ---------------------------------------------------------------------------
__global__ __launch_bounds__(256) void passW(const float* __restrict__ W,
                                             ushort* __restrict__ Wt)
{
    const int h = blockIdx.x, t = threadIdx.x;
    const int f = t & 63, g = t >> 6;
    const float* src = W + (long)h * 4096;
    ushort* dst = Wt + (long)h * 4096;
    #pragma unroll
    for (int i = 0; i < 16; ++i) {
        int d = g * 16 + i;
        dst[f * 64 + d] = f2bf(src[d * 64 + f]);
    }
}

// ---------------------------------------------------------------------------
// passA: phi(k) via MFMA (operands direct-from-global), dSt = v^T @ phi_k,
//        write bf16 wsS [d][f]; dZ fp32. ONE barrier.
// ---------------------------------------------------------------------------
__global__ __launch_bounds__(256) void passA(const float* __restrict__ K,
                                             const float* __restrict__ V,
                                             const ushort* __restrict__ Wt,
                                             ushort* __restrict__ wsS,
                                             float* __restrict__ wsZ)
{
    __shared__ __align__(16) char lds[24576];
    char* vT = lds;              // [64 d][64 s] bf16 swz7 (shared)
    char* pT = lds + 8192;       // [128 f][64 s] bf16 swz7 (shared)

    const int t = threadIdx.x, wv = t >> 6, l = t & 63, lr = l & 15, lg = l >> 4;
    const int bid = blockIdx.x, bh = bid >> 6, h = bh & (Hc - 1);
    const long base = (long)bh * (Lc * Dc) + (long)(bid & 63) * (Sc * Dc);

    stage_tr(V + base, vT, t);

    const float* kp = K + base;
    const ushort* wt = Wt + (long)h * 4096;

    // u = k @ W  (wave wv owns rows s in [16wv,16wv+16))
    short8 ak0 = gfrag_f32(kp, 16 * wv + lr, lg);
    short8 ak1 = gfrag_f32(kp, 16 * wv + lr, 4 + lg);
    f32x4 u0[4];
    #pragma unroll
    for (int tf = 0; tf < 4; ++tf) u0[tf] = zero4();
    #pragma unroll
    for (int tf = 0; tf < 4; ++tf) {
        u0[tf] = mfma(ak0, gfrag_bf16(wt, tf * 16 + lr, lg, 64), u0[tf]);
        u0[tf] = mfma(ak1, gfrag_bf16(wt, tf * 16 + lr, 4 + lg, 64), u0[tf]);
    }

    // dual softmax over f; lane holds rows lg*4+r (local), cols tf*16+lr
    float pp[4][4], pn[4][4];
    #pragma unroll
    for (int r = 0; r < 4; ++r) {
        float mx = fmaxf(fmaxf(u0[0][r], u0[1][r]), fmaxf(u0[2][r], u0[3][r]));
        float mn = fminf(fminf(u0[0][r], u0[1][r]), fminf(u0[2][r], u0[3][r]));
        #pragma unroll
        for (int m = 1; m < 16; m <<= 1) {
            mx = fmaxf(mx, __shfl_xor(mx, m, 16));
            mn = fminf(mn, __shfl_xor(mn, m, 16));
        }
        float sp = 0.f, sn = 0.f;
        #pragma unroll
        for (int tf = 0; tf < 4; ++tf) {
            pp[tf][r] = __expf(u0[tf][r] - mx); sp += pp[tf][r];
            pn[tf][r] = __expf(mn - u0[tf][r]); sn += pn[tf][r];
        }
        #pragma unroll
        for (int m = 1; m < 16; m <<= 1) {
            sp += __shfl_xor(sp, m, 16);
            sn += __shfl_xor(sn, m, 16);
        }
        float rp = 1.f / sp, rn = 1.f / sn;
        #pragma unroll
        for (int tf = 0; tf < 4; ++tf) { pp[tf][r] *= rp; pn[tf][r] *= rn; }
    }

    // write phi_k^T[f][s] (each wave writes its s-slice of every f row)
    #pragma unroll
    for (int tf = 0; tf < 4; ++tf)
        #pragma unroll
        for (int r = 0; r < 4; ++r) {
            int s = 16 * wv + lg * 4 + r;
            int f = tf * 16 + lr;
            *(ushort*)(pT + f * 128 + ((2 * s) ^ ((f & 7) << 4))) = f2bf(pp[tf][r]);
            int fn = 64 + f;
            *(ushort*)(pT + fn * 128 + ((2 * s) ^ ((fn & 7) << 4))) = f2bf(pn[tf][r]);
        }
    __syncthreads();

    // dSt[d][f] = v^T @ phi_k : wave owns d in [16wv,16wv+16), 8 f-tiles, K=64
    short8 av0 = ldfrag(vT, 16 * wv + lr, lg, 128, 7);
    short8 av1 = ldfrag(vT, 16 * wv + lr, 4 + lg, 128, 7);
    f32x4 acc[8];
    #pragma unroll
    for (int tf = 0; tf < 8; ++tf) acc[tf] = zero4();
    #pragma unroll
    for (int tf = 0; tf < 8; ++tf) {
        acc[tf] = mfma(av0, ldfrag(pT, tf * 16 + lr, lg, 128, 7), acc[tf]);
        acc[tf] = mfma(av1, ldfrag(pT, tf * 16 + lr, 4 + lg, 128, 7), acc[tf]);
    }
    ushort* o = wsS + (long)bid * (F2 * Dc);
    #pragma unroll
    for (int tf = 0; tf < 8; ++tf)
        #pragma unroll
        for (int r = 0; r < 4; ++r) {
            int d = 16 * wv + lg * 4 + r;
            o[d * 128 + tf * 16 + lr] = f2bf(acc[tf][r]);
        }

    // dZ[f] = row sums of phi_k^T (fp32)
    if (t < 128) {
        float z = 0.f;
        #pragma unroll
        for (int c = 0; c < 8; ++c) {
            short8 vv = ldfrag(pT, t, c, 128, 7);
            #pragma unroll
            for (int j = 0; j < 8; ++j) z += bf2f((ushort)vv[j]);
        }
        wsZ[(long)bid * F2 + t] = z;
    }
}

// ---------------------------------------------------------------------------
// passB: exclusive prefix over n per bh; register-batched (32 loads in flight).
// grid = 256 (S chunks) + 32 (Z blocks).
// ---------------------------------------------------------------------------
__global__ __launch_bounds__(256) void passB(ushort* __restrict__ wsS,
                                             float* __restrict__ wsZ)
{
    const int t = threadIdx.x;
    if (blockIdx.x >= 256) {                 // Z prefix
        const int bh = blockIdx.x - 256;
        if (t < 128) {
            float zc = 0.f, zb[32];
            #pragma unroll
            for (int h2 = 0; h2 < 2; ++h2) {
                float* zp = wsZ + ((long)bh * 64 + h2 * 32) * 128 + t;
                #pragma unroll
                for (int i = 0; i < 32; ++i) zb[i] = zp[i * 128];
                #pragma unroll
                for (int i = 0; i < 32; ++i) { float x = zb[i]; zp[i * 128] = zc; zc += x; }
            }
        }
        return;
    }
    const int bh = blockIdx.x >> 3, chunk = blockIdx.x & 7;
    ushort* p = wsS + (long)bh * 64 * 8192 + chunk * 1024 + t * 4;
    float c0 = 0.f, c1 = 0.f, c2 = 0.f, c3 = 0.f;
    ushort4v buf[32];
    #pragma unroll
    for (int h2 = 0; h2 < 2; ++h2) {
        ushort4v* pp = (ushort4v*)(p + (long)h2 * 32 * 8192);
        #pragma unroll
        for (int i = 0; i < 32; ++i) buf[i] = pp[i * 2048];
        #pragma unroll
        for (int i = 0; i < 32; ++i) {
            ushort4v x = buf[i];
            ushort4v cc;
            cc[0] = f2bf(c0); cc[1] = f2bf(c1); cc[2] = f2bf(c2); cc[3] = f2bf(c3);
            pp[i * 2048] = cc;
            c0 += bf2f(x[0]); c1 += bf2f(x[1]); c2 += bf2f(x[2]); c3 += bf2f(x[3]);
        }
    }
}

// ---------------------------------------------------------------------------
// passC: phi(q) + intra-block softmax + linear branch; operands direct from
// global except vT (shared LDS) and wave-local phi/a slices. ONE barrier.
// ---------------------------------------------------------------------------
__global__ __launch_bounds__(256) void passC(const float* __restrict__ Q,
                                             const float* __restrict__ K,
                                             const float* __restrict__ V,
                                             const ushort* __restrict__ Wt,
                                             const float* __restrict__ Alpha,
                                             const ushort* __restrict__ wsS,
                                             const float* __restrict__ wsZ,
                                             float* __restrict__ Out)
{
    __shared__ __align__(16) char lds[32768];
    char* vT = lds;                          // [64 d][64 t] bf16 swz7 (shared)
    const int t = threadIdx.x, wv = t >> 6, l = t & 63, lr = l & 15, lg = l >> 4;
    char* phiL = lds + 8192 + wv * 4096;     // per-wave [16 s][128 f] swz15
    char* aL   = lds + 24576 + wv * 2048;    // per-wave [16 s][64 t] swz7

    const int bid = blockIdx.x, bh = bid >> 6, h = bh & (Hc - 1);
    const long base = (long)bh * (Lc * Dc) + (long)(bid & 63) * (Sc * Dc);

    stage_tr(V + base, vT, t);

    const float* qp = Q + base;
    const float* kp = K + base;
    const ushort* wt = Wt + (long)h * 4096;
    const float* zp = wsZ + (long)bid * F2;

    float zv[4], zn[4];
    #pragma unroll
    for (int tf = 0; tf < 4; ++tf) { zv[tf] = zp[tf * 16 + lr]; zn[tf] = zp[64 + tf * 16 + lr]; }
    const float w = 1.f / (1.f + __expf(-Alpha[h]));

    // u = q@W, scores = q@k^T  (all operands direct from global)
    short8 aq0 = gfrag_f32(qp, 16 * wv + lr, lg);
    short8 aq1 = gfrag_f32(qp, 16 * wv + lr, 4 + lg);
    f32x4 u0[4], s0[4];
    #pragma unroll
    for (int tf = 0; tf < 4; ++tf) { u0[tf] = zero4(); s0[tf] = zero4(); }
    #pragma unroll
    for (int tf = 0; tf < 4; ++tf) {
        u0[tf] = mfma(aq0, gfrag_bf16(wt, tf * 16 + lr, lg, 64), u0[tf]);
        u0[tf] = mfma(aq1, gfrag_bf16(wt, tf * 16 + lr, 4 + lg, 64), u0[tf]);
        s0[tf] = mfma(aq0, gfrag_f32(kp, tf * 16 + lr, lg), s0[tf]);
        s0[tf] = mfma(aq1, gfrag_f32(kp, tf * 16 + lr, 4 + lg), s0[tf]);
    }

    float pp[4][4], pn[4][4], sden[4], lden[4];
    #pragma unroll
    for (int r = 0; r < 4; ++r) {
        float mx = fmaxf(fmaxf(u0[0][r], u0[1][r]), fmaxf(u0[2][r], u0[3][r]));
        float mn = fminf(fminf(u0[0][r], u0[1][r]), fminf(u0[2][r], u0[3][r]));
        #pragma unroll
        for (int m = 1; m < 16; m <<= 1) {
            mx = fmaxf(mx, __shfl_xor(mx, m, 16));
            mn = fminf(mn, __shfl_xor(mn, m, 16));
        }
        float sp = 0.f, sn = 0.f;
        #pragma unroll
        for (int tf = 0; tf < 4; ++tf) {
            pp[tf][r] = __expf(u0[tf][r] - mx); sp += pp[tf][r];
            pn[tf][r] = __expf(mn - u0[tf][r]); sn += pn[tf][r];
        }
        #pragma unroll
        for (int m = 1; m < 16; m <<= 1) {
            sp += __shfl_xor(sp, m, 16);
            sn += __shfl_xor(sn, m, 16);
        }
        float rp = 1.f / sp, rn = 1.f / sn;
        float zd = 0.f;
        #pragma unroll
        for (int tf = 0; tf < 4; ++tf) {
            pp[tf][r] *= rp; pn[tf][r] *= rn;
            zd += pp[tf][r] * zv[tf] + pn[tf][r] * zn[tf];
        }
        #pragma unroll
        for (int m = 1; m < 16; m <<= 1) zd += __shfl_xor(zd, m, 16);
        lden[r] = fmaxf(zd, EPSf);

        float sc[4];
        #pragma unroll
        for (int tf = 0; tf < 4; ++tf) sc[tf] = s0[tf][r] * SCALE;
        float m2 = fmaxf(fmaxf(sc[0], sc[1]), fmaxf(sc[2], sc[3]));
        #pragma unroll
        for (int m = 1; m < 16; m <<= 1) m2 = fmaxf(m2, __shfl_xor(m2, m, 16));
        float as = 0.f;
        #pragma unroll
        for (int tf = 0; tf < 4; ++tf) { sc[tf] = __expf(sc[tf] - m2); as += sc[tf]; }
        #pragma unroll
        for (int m = 1; m < 16; m <<= 1) as += __shfl_xor(as, m, 16);
        sden[r] = fmaxf(as, EPSf);
        #pragma unroll
        for (int tf = 0; tf < 4; ++tf) s0[tf][r] = sc[tf];   // stash exp(scores)
    }

    // wave-local frag writes (no barrier needed: same wave reads back)
    #pragma unroll
    for (int tf = 0; tf < 4; ++tf)
        #pragma unroll
        for (int r = 0; r < 4; ++r) {
            int sl = lg * 4 + r;                 // local row in [0,16)
            int f = tf * 16 + lr;
            *(ushort*)(phiL + sl * 256 + ((2 * f) ^ ((sl & 15) << 4))) = f2bf(pp[tf][r]);
            *(ushort*)(phiL + sl * 256 + ((2 * (64 + f)) ^ ((sl & 15) << 4))) = f2bf(pn[tf][r]);
            *(ushort*)(aL + sl * 128 + ((2 * f) ^ ((sl & 7) << 4))) = f2bf(s0[tf][r]);
        }

    __syncthreads();   // vT staged (issued long ago) before cross-wave B-frag reads

    // out = w*(a@v) + phi@S ; S^T B-frags direct from global wsS [d][f] bf16
    const ushort* Sg = wsS + (long)bid * (F2 * Dc);
    f32x4 acc[4];
    #pragma unroll
    for (int td = 0; td < 4; ++td) acc[td] = zero4();
    short8 aa0 = ldfrag(aL, lr, lg, 128, 7);
    short8 aa1 = ldfrag(aL, lr, 4 + lg, 128, 7);
    #pragma unroll
    for (int td = 0; td < 4; ++td) {
        acc[td] = mfma(aa0, ldfrag(vT, td * 16 + lr, lg, 128, 7), acc[td]);
        acc[td] = mfma(aa1, ldfrag(vT, td * 16 + lr, 4 + lg, 128, 7), acc[td]);
    }
    #pragma unroll
    for (int td = 0; td < 4; ++td)
        #pragma unroll
        for (int r = 0; r < 4; ++r) acc[td][r] *= w;

    short8 pf[4];
    #pragma unroll
    for (int kc = 0; kc < 4; ++kc) pf[kc] = ldfrag(phiL, lr, kc * 4 + lg, 256, 15);
    #pragma unroll
    for (int td = 0; td < 4; ++td)
        #pragma unroll
        for (int kc = 0; kc < 4; ++kc)
            acc[td] = mfma(pf[kc], gfrag_bf16(Sg, td * 16 + lr, kc * 4 + lg, 128), acc[td]);

    float* op = Out + base;
    #pragma unroll
    for (int r = 0; r < 4; ++r) {
        int s = 16 * wv + lg * 4 + r;
        float den = fmaxf(w * sden[r] + lden[r], EPSf);
        float inv = 1.f / den;
        #pragma unroll
        for (int td = 0; td < 4; ++td)
            op[s * 64 + td * 16 + lr] = acc[td][r] * inv;
    }
}

// ---------------------------------------------------------------------------
extern "C" void kernel_launch(void* const* d_in, const int* in_sizes, int n_in,
                              void* d_out, int out_size, void* d_ws, size_t ws_size,
                              hipStream_t stream)
{
    const float* q     = (const float*)d_in[0];
    const float* k     = (const float*)d_in[1];
    const float* v     = (const float*)d_in[2];
    const float* W     = (const float*)d_in[3];
    const float* alpha = (const float*)d_in[4];
    float* out = (float*)d_out;

    ushort* wsSb = (ushort*)d_ws;                                   // 32 MB
    float*  wsZ  = (float*)((char*)d_ws + (size_t)NBLK * F2 * Dc * 2);   // 1 MB
    ushort* Wtb  = (ushort*)((char*)wsZ + (size_t)NBLK * F2 * 4);   // 128 KB

    passW<<<Hc, 256, 0, stream>>>(W, Wtb);
    passA<<<NBLK, 256, 0, stream>>>(k, v, Wtb, wsSb, wsZ);
    passB<<<288, 256, 0, stream>>>(wsSb, wsZ);
    passC<<<NBLK, 256, 0, stream>>>(q, k, v, Wtb, alpha, wsSb, wsZ, out);
}